// Round 4
// baseline (885.601 us; speedup 1.0000x reference)
//
#include <hip/hip_runtime.h>
#include <hip/hip_cooperative_groups.h>
#include <math.h>

namespace cg = cooperative_groups;

// Problem constants
#define B_ 512
#define I_ 8
#define C_ 1152
#define U_ 10
#define O_ 16
#define K_ (I_*C_)          // 9216 (k = i*1152 + c)
#define UO_ (U_*O_)         // 160
#define KSPLIT 12
#define KCHUNK (K_/KSPLIT)  // 768 = 24*32
#define NBLK 512
#define NTHR 256

typedef short bf16x8 __attribute__((ext_vector_type(8)));
typedef float f32x4 __attribute__((ext_vector_type(4)));
typedef unsigned short u16x8 __attribute__((ext_vector_type(8)));

// ---- persistent device scratch (fully overwritten every call) ----
__device__ __attribute__((aligned(16))) unsigned short g_xb[B_*K_];   // bf16 x  [b][k]
__device__ __attribute__((aligned(16))) unsigned short g_xT[K_*B_];   // bf16 x^T [k][b]
__device__ __attribute__((aligned(16))) unsigned short g_Wtb[1280*C_];// bf16 W^T [uoi][c]
__device__ __attribute__((aligned(16))) unsigned short g_Wcb[UO_*K_]; // bf16 Wc [uo][k] (== [uoi][c])
__device__ float g_b[C_*U_];                                          // logits [c][u]
__device__ __attribute__((aligned(16))) float g_cwT[U_*C_];           // softmax weights [u][c]
__device__ __attribute__((aligned(16))) float g_spart[KSPLIT][B_*UO_];
__device__ __attribute__((aligned(16))) unsigned short g_vT[UO_*B_];  // bf16 v^T [uo][b]
__device__ __attribute__((aligned(16))) float g_T[K_*UO_];            // fp32 T [k][uo]

__device__ __forceinline__ unsigned short f2bf(float f) {
    unsigned u = __builtin_bit_cast(unsigned, f);
    unsigned r = (u + 0x7FFFu + ((u >> 16) & 1u)) >> 16;
    return (unsigned short)r;
}
__device__ __forceinline__ float bf2f(unsigned short h) {
    unsigned u = ((unsigned)h) << 16;
    return __builtin_bit_cast(float, u);
}

// ---- phase: prep. x -> bf16 [b][k] + [k][b]; W -> bf16 W^T; Wc(t=0) = 0.1*W^T ----
__device__ void ph_prep(const float* __restrict__ x, const float* __restrict__ W,
                        int bid, int nb, int tid) {
    __shared__ float tile[32][33];
    int tx = tid & 31, ty = tid >> 5;
    for (int task = bid; task < 6048; task += nb) {
        if (task < 4608) {                      // x tiles: 16 (b) x 288 (k)
            int b0 = (task & 15) * 32;
            int k0 = (task >> 4) * 32;
            #pragma unroll
            for (int j = 0; j < 4; j++) {
                int r = ty + 8*j;
                float f = x[(b0+r)*K_ + k0+tx];
                tile[r][tx] = f;
                g_xb[(b0+r)*K_ + k0+tx] = f2bf(f);
            }
            __syncthreads();
            #pragma unroll
            for (int j = 0; j < 4; j++) {
                int r = ty + 8*j;               // k within tile
                g_xT[(k0+r)*B_ + b0+tx] = f2bf(tile[tx][r]);
            }
            __syncthreads();
        } else {                                // W tiles: 40 (uoi) x 36 (c)
            int q = task - 4608;
            int r0 = (q % 40) * 32;
            int c0 = (q / 40) * 32;
            #pragma unroll
            for (int j = 0; j < 4; j++)
                tile[ty+8*j][tx] = W[(c0+ty+8*j)*1280 + r0+tx];
            __syncthreads();
            #pragma unroll
            for (int j = 0; j < 4; j++) {
                float f = tile[tx][ty+8*j];
                g_Wtb[(r0+ty+8*j)*C_ + c0+tx] = f2bf(f);
                g_Wcb[(r0+ty+8*j)*C_ + c0+tx] = f2bf(0.1f*f);   // uniform softmax at t=0
            }
            __syncthreads();
        }
    }
}

// ---- phase: s-GEMM. spart[kz][b][uo] = sum_k x[b][k]*Wc[uo][k]; 480 tasks ----
__device__ void ph_sgemm(int bid, int tid) {
    if (bid >= 480) return;
    int lane = tid & 63, wid = tid >> 6;
    int mi = bid & 7;
    int rest = bid >> 3;
    int ni = rest % 5;
    int kz = rest / 5;
    int m0 = mi*64 + wid*16;
    int n0 = ni*32;
    int k0 = kz*KCHUNK;
    int ra = lane & 15;
    int ko = (lane >> 4) * 8;
    const unsigned short* pa  = g_xb  + (m0+ra)*K_ + k0 + ko;
    const unsigned short* pb0 = g_Wcb + (n0+ra)*K_ + k0 + ko;
    const unsigned short* pb1 = pb0 + 16*K_;
    f32x4 acc0 = {0.f,0.f,0.f,0.f};
    f32x4 acc1 = {0.f,0.f,0.f,0.f};
    #pragma unroll 6
    for (int s = 0; s < KCHUNK/32; s++) {
        bf16x8 a  = *(const bf16x8*)pa;
        bf16x8 b0 = *(const bf16x8*)pb0;
        bf16x8 b1 = *(const bf16x8*)pb1;
        acc0 = __builtin_amdgcn_mfma_f32_16x16x32_bf16(a, b0, acc0, 0, 0, 0);
        acc1 = __builtin_amdgcn_mfma_f32_16x16x32_bf16(a, b1, acc1, 0, 0, 0);
        pa += 32; pb0 += 32; pb1 += 32;
    }
    int row = (lane >> 4) * 4;
    int col = lane & 15;
    float* outp = &g_spart[kz][0];
    #pragma unroll
    for (int r = 0; r < 4; r++) {
        outp[(m0+row+r)*UO_ + n0 + col]      = acc0[r];
        outp[(m0+row+r)*UO_ + n0 + 16 + col] = acc1[r];
    }
}

// ---- phase: reduce split-K + squash -> vT bf16 (+ final out) ----
__device__ void ph_squash(float* __restrict__ out, int write_out, int bid, int nb, int tid) {
    for (int task = bid; task < 20; task += nb) {
        int g = task*NTHR + tid;            // 5120 = 512*10
        int u = g >> 9;
        int b = g & 511;
        float t[O_];
        #pragma unroll
        for (int o = 0; o < O_; o++) t[o] = 0.f;
        #pragma unroll
        for (int ks = 0; ks < KSPLIT; ks++) {
            const f32x4* p = (const f32x4*)&g_spart[ks][b*UO_ + u*O_];
            #pragma unroll
            for (int q = 0; q < 4; q++) {
                f32x4 v4 = p[q];
                t[q*4+0] += v4[0]; t[q*4+1] += v4[1]; t[q*4+2] += v4[2]; t[q*4+3] += v4[3];
            }
        }
        float norm = 0.f;
        #pragma unroll
        for (int o = 0; o < O_; o++) norm += t[o]*t[o];
        float f = norm / ((1.f + norm) * sqrtf(norm));
        #pragma unroll
        for (int o = 0; o < O_; o++) {
            float vv = t[o] * f;
            g_vT[(u*O_+o)*B_ + b] = f2bf(vv);
            if (write_out) out[(b*U_+u)*O_ + o] = vv;
        }
    }
}

// ---- phase: T-GEMM. T[k][uo] = sum_b xT[k][b]*vT[uo][b]; 360 tasks ----
__device__ void ph_tgemm(int bid, int tid) {
    if (bid >= 360) return;
    int lane = tid & 63, wid = tid >> 6;
    int mi = bid % 72;
    int ni = bid / 72;
    int m0 = mi*128 + wid*32;
    int n0 = ni*32;
    int ra = lane & 15;
    int ko = (lane >> 4) * 8;
    const unsigned short* pa0 = g_xT + (m0+ra)*B_ + ko;
    const unsigned short* pa1 = pa0 + 16*B_;
    const unsigned short* pb0 = g_vT + (n0+ra)*B_ + ko;
    const unsigned short* pb1 = pb0 + 16*B_;
    f32x4 acc00 = {0.f,0.f,0.f,0.f}, acc01 = {0.f,0.f,0.f,0.f};
    f32x4 acc10 = {0.f,0.f,0.f,0.f}, acc11 = {0.f,0.f,0.f,0.f};
    #pragma unroll 8
    for (int s = 0; s < B_/32; s++) {
        bf16x8 a0 = *(const bf16x8*)pa0;
        bf16x8 a1 = *(const bf16x8*)pa1;
        bf16x8 b0 = *(const bf16x8*)pb0;
        bf16x8 b1 = *(const bf16x8*)pb1;
        acc00 = __builtin_amdgcn_mfma_f32_16x16x32_bf16(a0, b0, acc00, 0, 0, 0);
        acc01 = __builtin_amdgcn_mfma_f32_16x16x32_bf16(a0, b1, acc01, 0, 0, 0);
        acc10 = __builtin_amdgcn_mfma_f32_16x16x32_bf16(a1, b0, acc10, 0, 0, 0);
        acc11 = __builtin_amdgcn_mfma_f32_16x16x32_bf16(a1, b1, acc11, 0, 0, 0);
        pa0 += 32; pa1 += 32; pb0 += 32; pb1 += 32;
    }
    int row = (lane >> 4) * 4;
    int col = lane & 15;
    #pragma unroll
    for (int r = 0; r < 4; r++) {
        g_T[(m0+row+r)*UO_ + n0 + col]         = acc00[r];
        g_T[(m0+row+r)*UO_ + n0 + 16 + col]    = acc01[r];
        g_T[(m0+16+row+r)*UO_ + n0 + col]      = acc10[r];
        g_T[(m0+16+row+r)*UO_ + n0 + 16 + col] = acc11[r];
    }
}

// ---- phase: b-update + fused softmax -> cwT; one task per channel c ----
__device__ void ph_bupdate(const float* __restrict__ W, int first, int bid, int nb, int tid) {
    __shared__ float Ts[I_][UO_];
    __shared__ float bl[U_];
    for (int c = bid; c < C_; c += nb) {
        for (int idx = tid; idx < I_*UO_; idx += NTHR) {
            int i = idx / UO_, j = idx - i*UO_;
            Ts[i][j] = g_T[(i*C_ + c)*UO_ + j];
        }
        __syncthreads();
        if (tid < 160) {
            int u = tid >> 4, h = tid & 15;     // h = o
            const float* wp = W + c*1280 + u*128 + h*8;
            float4 w0 = *(const float4*)wp;
            float4 w1 = *(const float4*)(wp + 4);
            const float* ts = &Ts[0][u*16 + h];
            float sum = w0.x*ts[0*UO_] + w0.y*ts[1*UO_] + w0.z*ts[2*UO_] + w0.w*ts[3*UO_]
                      + w1.x*ts[4*UO_] + w1.y*ts[5*UO_] + w1.z*ts[6*UO_] + w1.w*ts[7*UO_];
            #pragma unroll
            for (int d = 8; d >= 1; d >>= 1) sum += __shfl_down(sum, d, 16);
            if (h == 0) {
                float val = sum * (1.f/512.f);
                if (!first) val += g_b[c*U_ + u];
                g_b[c*U_ + u] = val;
                bl[u] = val;
            }
        }
        __syncthreads();
        if (tid == 0) {
            float m = bl[0];
            #pragma unroll
            for (int u = 1; u < U_; u++) m = fmaxf(m, bl[u]);
            float e[U_]; float s = 0.f;
            #pragma unroll
            for (int u = 0; u < U_; u++) { e[u] = expf(bl[u]-m); s += e[u]; }
            float inv = 1.f/s;
            #pragma unroll
            for (int u = 0; u < U_; u++) g_cwT[u*C_ + c] = e[u]*inv;
        }
        __syncthreads();
    }
}

// ---- phase: Wc[uoi][c] = cwT[u][c] * Wtb[uoi][c] (bf16), u16x8 chunks ----
__device__ void ph_buildWc(int bid, int nb, int tid) {
    const int total = 1280 * (C_/8);   // 184320 chunks
    for (int g = bid*NTHR + tid; g < total; g += nb*NTHR) {
        int row = g / (C_/8);
        int c0 = (g - row*(C_/8)) * 8;
        int u = row >> 7;
        u16x8 w = *(const u16x8*)(g_Wtb + row*C_ + c0);
        const float* cw = g_cwT + u*C_ + c0;
        float4 ca = *(const float4*)cw;
        float4 cb = *(const float4*)(cw + 4);
        u16x8 o;
        o[0] = f2bf(bf2f(w[0])*ca.x); o[1] = f2bf(bf2f(w[1])*ca.y);
        o[2] = f2bf(bf2f(w[2])*ca.z); o[3] = f2bf(bf2f(w[3])*ca.w);
        o[4] = f2bf(bf2f(w[4])*cb.x); o[5] = f2bf(bf2f(w[5])*cb.y);
        o[6] = f2bf(bf2f(w[6])*cb.z); o[7] = f2bf(bf2f(w[7])*cb.w);
        *(u16x8*)(g_Wcb + row*C_ + c0) = o;
    }
}

// ---- the megakernel: everything, with grid-wide syncs between phases ----
__global__ __launch_bounds__(NTHR, 2) void k_mega(const float* __restrict__ x,
                                                  const float* __restrict__ W,
                                                  float* __restrict__ out) {
    cg::grid_group grid = cg::this_grid();
    int bid = blockIdx.x, tid = threadIdx.x;
    int nb = gridDim.x;
    ph_prep(x, W, bid, nb, tid);
    grid.sync();
    for (int t = 0; t < 3; t++) {
        ph_sgemm(bid, tid);
        grid.sync();
        ph_squash(out, t == 2 ? 1 : 0, bid, nb, tid);
        if (t == 2) break;
        grid.sync();
        ph_tgemm(bid, tid);
        grid.sync();
        ph_bupdate(W, t == 0 ? 1 : 0, bid, nb, tid);
        grid.sync();
        ph_buildWc(bid, nb, tid);
        grid.sync();
    }
}

// ---- fallback wrappers (used only if cooperative launch is rejected) ----
__global__ __launch_bounds__(NTHR) void w_prep(const float* __restrict__ x, const float* __restrict__ W) {
    ph_prep(x, W, blockIdx.x, gridDim.x, threadIdx.x);
}
__global__ __launch_bounds__(NTHR) void w_sgemm() { ph_sgemm(blockIdx.x, threadIdx.x); }
__global__ __launch_bounds__(NTHR) void w_squash(float* __restrict__ out, int wo) {
    ph_squash(out, wo, blockIdx.x, gridDim.x, threadIdx.x);
}
__global__ __launch_bounds__(NTHR) void w_tgemm() { ph_tgemm(blockIdx.x, threadIdx.x); }
__global__ __launch_bounds__(NTHR) void w_bupdate(const float* __restrict__ W, int first) {
    ph_bupdate(W, first, blockIdx.x, gridDim.x, threadIdx.x);
}
__global__ __launch_bounds__(NTHR) void w_buildWc() { ph_buildWc(blockIdx.x, gridDim.x, threadIdx.x); }

extern "C" void kernel_launch(void* const* d_in, const int* in_sizes, int n_in,
                              void* d_out, int out_size, void* d_ws, size_t ws_size,
                              hipStream_t stream) {
    const float* x = (const float*)d_in[0];
    const float* W = (const float*)d_in[1];
    float* out = (float*)d_out;

    void* kargs[3] = { (void*)&x, (void*)&W, (void*)&out };
    hipError_t e = hipLaunchCooperativeKernel((const void*)k_mega, dim3(NBLK), dim3(NTHR),
                                              kargs, 0u, stream);
    if (e != hipSuccess) {
        // fallback: same phases as separate kernels
        w_prep<<<dim3(NBLK), dim3(NTHR), 0, stream>>>(x, W);
        for (int t = 0; t < 3; t++) {
            w_sgemm<<<dim3(480), dim3(NTHR), 0, stream>>>();
            w_squash<<<dim3(20), dim3(NTHR), 0, stream>>>(out, t == 2 ? 1 : 0);
            if (t < 2) {
                w_tgemm<<<dim3(360), dim3(NTHR), 0, stream>>>();
                w_bupdate<<<dim3(NBLK), dim3(NTHR), 0, stream>>>(W, t == 0 ? 1 : 0);
                w_buildWc<<<dim3(NBLK), dim3(NTHR), 0, stream>>>();
            }
        }
    }
}

// Round 5
// 163.590 us; speedup vs baseline: 5.4135x; 5.4135x over previous
//
#include <hip/hip_runtime.h>
#include <math.h>

// Problem constants
#define B_ 512
#define I_ 8
#define C_ 1152
#define U_ 10
#define O_ 16
#define K_ (I_*C_)          // 9216 (k = i*1152 + c)
#define UO_ (U_*O_)         // 160
#define KSPLIT 12
#define KCHUNK (K_/KSPLIT)  // 768 = 24*32

typedef short bf16x8 __attribute__((ext_vector_type(8)));
typedef float f32x4 __attribute__((ext_vector_type(4)));
typedef unsigned short u16x8 __attribute__((ext_vector_type(8)));

// ---- persistent device scratch (fully overwritten every call) ----
__device__ __attribute__((aligned(16))) unsigned short g_xb[B_*K_];    // bf16 x  [b][k]
__device__ __attribute__((aligned(16))) unsigned short g_xT[K_*B_];    // bf16 x^T [k][b]
__device__ __attribute__((aligned(16))) unsigned short g_Wtb[1280*C_]; // bf16 W^T [uoi][c] == [uo][k]
__device__ float g_b[C_*U_];                                           // logits [c][u]
__device__ __attribute__((aligned(16))) float g_cwT[U_*C_];            // softmax weights [u][c] fp32
__device__ __attribute__((aligned(16))) float g_spart[KSPLIT][B_*UO_];
__device__ __attribute__((aligned(16))) unsigned short g_vT[UO_*B_];   // bf16 v^T [uo][b]
__device__ __attribute__((aligned(16))) float g_T[K_*UO_];             // fp32 T [k][uo]

__device__ __forceinline__ unsigned short f2bf(float f) {
    unsigned u = __builtin_bit_cast(unsigned, f);
    unsigned r = (u + 0x7FFFu + ((u >> 16) & 1u)) >> 16;
    return (unsigned short)r;
}
__device__ __forceinline__ float bf2f(unsigned short h) {
    unsigned u = ((unsigned)h) << 16;
    return __builtin_bit_cast(float, u);
}

// ---- one-time prep: x -> bf16 [b][k] + [k][b]; W -> bf16 W^T [uoi][c] ----
__global__ __launch_bounds__(256) void k_prep(const float* __restrict__ x,
                                              const float* __restrict__ W) {
    __shared__ float tile[32][33];
    int tid = threadIdx.x, tx = tid & 31, ty = tid >> 5;
    for (int task = blockIdx.x; task < 6048; task += gridDim.x) {
        if (task < 4608) {                      // x tiles: 16 (b) x 288 (k)
            int b0 = (task & 15) * 32;
            int k0 = (task >> 4) * 32;
            #pragma unroll
            for (int j = 0; j < 4; j++) {
                int r = ty + 8*j;
                float f = x[(b0+r)*K_ + k0+tx];
                tile[r][tx] = f;
                g_xb[(b0+r)*K_ + k0+tx] = f2bf(f);
            }
            __syncthreads();
            #pragma unroll
            for (int j = 0; j < 4; j++) {
                int r = ty + 8*j;               // k within tile
                g_xT[(k0+r)*B_ + b0+tx] = f2bf(tile[tx][r]);
            }
            __syncthreads();
        } else {                                // W tiles: 40 (uoi) x 36 (c)
            int q = task - 4608;
            int r0 = (q % 40) * 32;
            int c0 = (q / 40) * 32;
            #pragma unroll
            for (int j = 0; j < 4; j++)
                tile[ty+8*j][tx] = W[(c0+ty+8*j)*1280 + r0+tx];
            __syncthreads();
            #pragma unroll
            for (int j = 0; j < 4; j++)
                g_Wtb[(r0+ty+8*j)*C_ + c0+tx] = f2bf(tile[tx][ty+8*j]);
            __syncthreads();
        }
    }
}

// ---- s-GEMM with fused cw-scaling of W^T.
// spart[kz][b][uo] = sum_{k in chunk} x[b][k] * (cw[c(k),u] * Wt[uo][k])
// 240 blocks = 4(mi) x 5(ni) x 12(kz); 4 waves; wave tile 32(M) x 32(N).
template<int UNI>
__global__ __launch_bounds__(256) void k_sgemm() {
    int tid = threadIdx.x, lane = tid & 63, wid = tid >> 6;
    int bid = blockIdx.x;
    int mi = bid & 3;
    int rest = bid >> 2;
    int ni = rest % 5;
    int kz = rest / 5;
    int m0 = mi*128 + wid*32;
    int n0 = ni*32;
    int k0 = kz*KCHUNK;
    int ra = lane & 15;
    int ko = (lane >> 4) * 8;

    const unsigned short* pa0 = g_xb  + (m0+ra)*K_ + k0 + ko;
    const unsigned short* pa1 = pa0 + 16*K_;
    const unsigned short* pw0 = g_Wtb + (n0+ra)*K_ + k0 + ko;
    const unsigned short* pw1 = pw0 + 16*K_;
    int u0 = n0 >> 4;                    // B0 rows all have u=u0, B1 rows u0+1
    int c = k0 % 1152;                   // channel index of fragment base (wave-uniform wrap)
    const float* pc0 = g_cwT + u0*C_ + c + ko;
    const float* pc1 = pc0 + C_;

    f32x4 acc00 = {0.f,0.f,0.f,0.f}, acc01 = {0.f,0.f,0.f,0.f};
    f32x4 acc10 = {0.f,0.f,0.f,0.f}, acc11 = {0.f,0.f,0.f,0.f};

    #pragma unroll 6
    for (int s = 0; s < KCHUNK/32; s++) {
        u16x8 w0 = *(const u16x8*)pw0;
        u16x8 w1 = *(const u16x8*)pw1;
        bf16x8 a0 = *(const bf16x8*)pa0;
        bf16x8 a1 = *(const bf16x8*)pa1;
        bf16x8 b0, b1;
        if (UNI) {
            #pragma unroll
            for (int j = 0; j < 8; j++) {
                b0[j] = (short)f2bf(bf2f(w0[j]) * 0.1f);
                b1[j] = (short)f2bf(bf2f(w1[j]) * 0.1f);
            }
        } else {
            float4 qa0 = *(const float4*)pc0;
            float4 qb0 = *(const float4*)(pc0 + 4);
            float4 qa1 = *(const float4*)pc1;
            float4 qb1 = *(const float4*)(pc1 + 4);
            float q0[8] = {qa0.x,qa0.y,qa0.z,qa0.w,qb0.x,qb0.y,qb0.z,qb0.w};
            float q1[8] = {qa1.x,qa1.y,qa1.z,qa1.w,qb1.x,qb1.y,qb1.z,qb1.w};
            #pragma unroll
            for (int j = 0; j < 8; j++) {
                b0[j] = (short)f2bf(bf2f(w0[j]) * q0[j]);
                b1[j] = (short)f2bf(bf2f(w1[j]) * q1[j]);
            }
        }
        acc00 = __builtin_amdgcn_mfma_f32_16x16x32_bf16(a0, b0, acc00, 0, 0, 0);
        acc01 = __builtin_amdgcn_mfma_f32_16x16x32_bf16(a0, b1, acc01, 0, 0, 0);
        acc10 = __builtin_amdgcn_mfma_f32_16x16x32_bf16(a1, b0, acc10, 0, 0, 0);
        acc11 = __builtin_amdgcn_mfma_f32_16x16x32_bf16(a1, b1, acc11, 0, 0, 0);
        pa0 += 32; pa1 += 32; pw0 += 32; pw1 += 32;
        c += 32; pc0 += 32; pc1 += 32;
        if (c >= 1152) { c -= 1152; pc0 -= 1152; pc1 -= 1152; }   // wave-uniform branch
    }
    int row = (lane >> 4) * 4;
    int col = lane & 15;
    float* outp = &g_spart[kz][0];
    #pragma unroll
    for (int r = 0; r < 4; r++) {
        outp[(m0+row+r)*UO_ + n0 + col]         = acc00[r];
        outp[(m0+row+r)*UO_ + n0 + 16 + col]    = acc01[r];
        outp[(m0+16+row+r)*UO_ + n0 + col]      = acc10[r];
        outp[(m0+16+row+r)*UO_ + n0 + 16 + col] = acc11[r];
    }
}

// ---- reduce split-K + squash -> vT bf16 (+ final out) ----
__global__ __launch_bounds__(256) void k_squash(float* __restrict__ out, int write_out) {
    int g = blockIdx.x*256 + threadIdx.x;   // 5120 = 512*10
    if (g >= B_*U_) return;
    int u = g >> 9;
    int b = g & 511;
    float t[O_];
    #pragma unroll
    for (int o = 0; o < O_; o++) t[o] = 0.f;
    #pragma unroll
    for (int ks = 0; ks < KSPLIT; ks++) {
        const f32x4* p = (const f32x4*)&g_spart[ks][b*UO_ + u*O_];
        #pragma unroll
        for (int q = 0; q < 4; q++) {
            f32x4 v4 = p[q];
            t[q*4+0] += v4[0]; t[q*4+1] += v4[1]; t[q*4+2] += v4[2]; t[q*4+3] += v4[3];
        }
    }
    float norm = 0.f;
    #pragma unroll
    for (int o = 0; o < O_; o++) norm += t[o]*t[o];
    float f = norm / ((1.f + norm) * sqrtf(norm));
    #pragma unroll
    for (int o = 0; o < O_; o++) {
        float vv = t[o] * f;
        g_vT[(u*O_+o)*B_ + b] = f2bf(vv);
        if (write_out) out[(b*U_+u)*O_ + o] = vv;
    }
}

// ---- T-GEMM: T[k][uo] = sum_b xT[k][b]*vT[uo][b]  (M=9216,N=160,K=512) ----
// 360 blocks = 72(mi) x 5(ni); 4 waves; wave tile 32 x 32.
__global__ __launch_bounds__(256) void k_tgemm() {
    int tid = threadIdx.x, lane = tid & 63, wid = tid >> 6;
    int bid = blockIdx.x;
    int mi = bid % 72;
    int ni = bid / 72;
    int m0 = mi*128 + wid*32;
    int n0 = ni*32;
    int ra = lane & 15;
    int ko = (lane >> 4) * 8;
    const unsigned short* pa0 = g_xT + (m0+ra)*B_ + ko;
    const unsigned short* pa1 = pa0 + 16*B_;
    const unsigned short* pb0 = g_vT + (n0+ra)*B_ + ko;
    const unsigned short* pb1 = pb0 + 16*B_;
    f32x4 acc00 = {0.f,0.f,0.f,0.f}, acc01 = {0.f,0.f,0.f,0.f};
    f32x4 acc10 = {0.f,0.f,0.f,0.f}, acc11 = {0.f,0.f,0.f,0.f};
    #pragma unroll 8
    for (int s = 0; s < B_/32; s++) {
        bf16x8 a0 = *(const bf16x8*)pa0;
        bf16x8 a1 = *(const bf16x8*)pa1;
        bf16x8 b0 = *(const bf16x8*)pb0;
        bf16x8 b1 = *(const bf16x8*)pb1;
        acc00 = __builtin_amdgcn_mfma_f32_16x16x32_bf16(a0, b0, acc00, 0, 0, 0);
        acc01 = __builtin_amdgcn_mfma_f32_16x16x32_bf16(a0, b1, acc01, 0, 0, 0);
        acc10 = __builtin_amdgcn_mfma_f32_16x16x32_bf16(a1, b0, acc10, 0, 0, 0);
        acc11 = __builtin_amdgcn_mfma_f32_16x16x32_bf16(a1, b1, acc11, 0, 0, 0);
        pa0 += 32; pa1 += 32; pb0 += 32; pb1 += 32;
    }
    int row = (lane >> 4) * 4;
    int col = lane & 15;
    #pragma unroll
    for (int r = 0; r < 4; r++) {
        g_T[(m0+row+r)*UO_ + n0 + col]         = acc00[r];
        g_T[(m0+row+r)*UO_ + n0 + 16 + col]    = acc01[r];
        g_T[(m0+16+row+r)*UO_ + n0 + col]      = acc10[r];
        g_T[(m0+16+row+r)*UO_ + n0 + 16 + col] = acc11[r];
    }
}

// ---- b-update + fused softmax -> cwT fp32; one block per channel c ----
__global__ __launch_bounds__(256) void k_bupdate(const float* __restrict__ W, int first) {
    __shared__ float Ts[I_][UO_];
    __shared__ float bl[U_];
    int c = blockIdx.x;
    int tid = threadIdx.x;
    for (int idx = tid; idx < I_*UO_; idx += 256) {
        int i = idx / UO_, j = idx - i*UO_;
        Ts[i][j] = g_T[(i*C_ + c)*UO_ + j];
    }
    __syncthreads();
    if (tid < 160) {
        int u = tid >> 4, h = tid & 15;     // h = o
        const float* wp = W + c*1280 + u*128 + h*8;
        float4 w0 = *(const float4*)wp;
        float4 w1 = *(const float4*)(wp + 4);
        const float* ts = &Ts[0][u*16 + h];
        float sum = w0.x*ts[0*UO_] + w0.y*ts[1*UO_] + w0.z*ts[2*UO_] + w0.w*ts[3*UO_]
                  + w1.x*ts[4*UO_] + w1.y*ts[5*UO_] + w1.z*ts[6*UO_] + w1.w*ts[7*UO_];
        #pragma unroll
        for (int d = 8; d >= 1; d >>= 1) sum += __shfl_down(sum, d, 16);
        if (h == 0) {
            float val = sum * (1.f/512.f);
            if (!first) val += g_b[c*U_ + u];
            g_b[c*U_ + u] = val;
            bl[u] = val;
        }
    }
    __syncthreads();
    if (tid == 0) {
        float m = bl[0];
        #pragma unroll
        for (int u = 1; u < U_; u++) m = fmaxf(m, bl[u]);
        float e[U_]; float s = 0.f;
        #pragma unroll
        for (int u = 0; u < U_; u++) { e[u] = expf(bl[u]-m); s += e[u]; }
        float inv = 1.f/s;
        #pragma unroll
        for (int u = 0; u < U_; u++) g_cwT[u*C_ + c] = e[u]*inv;
    }
}

extern "C" void kernel_launch(void* const* d_in, const int* in_sizes, int n_in,
                              void* d_out, int out_size, void* d_ws, size_t ws_size,
                              hipStream_t stream) {
    const float* x = (const float*)d_in[0];
    const float* W = (const float*)d_in[1];
    float* out = (float*)d_out;

    k_prep<<<dim3(512), dim3(256), 0, stream>>>(x, W);

    for (int t = 0; t < 3; t++) {
        if (t == 0) k_sgemm<1><<<dim3(240), dim3(256), 0, stream>>>();
        else        k_sgemm<0><<<dim3(240), dim3(256), 0, stream>>>();
        k_squash<<<dim3(20), dim3(256), 0, stream>>>(out, t == 2 ? 1 : 0);
        if (t < 2) {
            k_tgemm<<<dim3(360), dim3(256), 0, stream>>>();
            k_bupdate<<<dim3(1152), dim3(256), 0, stream>>>(W, t == 0 ? 1 : 0);
        }
    }
}

// Round 6
// 120.175 us; speedup vs baseline: 7.3692x; 1.3613x over previous
//
#include <hip/hip_runtime.h>
#include <math.h>

// Problem constants.  Contraction index k' = c*8 + i  (c-major!) so that the
// B-matrix [uo][k'] is exactly W's native [c][u][o][i] layout, elementwise-scaled.
#define B_ 512
#define C_ 1152
#define U_ 10
#define O_ 16
#define I_ 8
#define K_ 9216
#define UO_ 160

typedef short bf16x8 __attribute__((ext_vector_type(8)));
typedef float f32x4 __attribute__((ext_vector_type(4)));
typedef unsigned short u16x8v __attribute__((ext_vector_type(8)));

// ---- persistent device scratch (fully overwritten every call) ----
__device__ __attribute__((aligned(16))) unsigned short g_xb2[B_*K_];  // bf16 x [b][k']
__device__ __attribute__((aligned(16))) unsigned short g_xT2[K_*B_];  // bf16 x^T [k'][b]
__device__ __attribute__((aligned(16))) unsigned short g_Wc[C_*1280]; // bf16 cw-scaled W, native layout [c][u][o][i]
__device__ __attribute__((aligned(16))) unsigned short g_vT[UO_*B_];  // bf16 v^T [uo][b]
__device__ float g_b[C_*U_];                                          // routing logits [c][u]

__device__ __forceinline__ unsigned short f2bf(float f) {
    unsigned u = __builtin_bit_cast(unsigned, f);
    unsigned r = (u + 0x7FFFu + ((u >> 16) & 1u)) >> 16;
    return (unsigned short)r;
}

// ---- one-time prep ----
// tasks 0..575:   x [b][i][c] -> xb2 [b][(c,i)] bf16  AND  xT2 [(c,i)][b] bf16
//                 (576 = 16 b-tiles x 36 c-tiles of 32b x 32c x 8i)
// tasks 576..755: Wc = bf16(0.1 * W) elementwise (t=0 softmax is uniform 1/10)
__global__ __launch_bounds__(256) void k_prep(const float* __restrict__ x,
                                              const float* __restrict__ W) {
    int task = blockIdx.x, tid = threadIdx.x;
    if (task < 576) {
        __shared__ unsigned short lds[32*256];   // [b][j=c*8+i], XOR-swizzled
        int b0 = (task & 15) * 32;
        int c0 = (task >> 4) * 32;
        int li = tid >> 5, lc = tid & 31;
        for (int rep = 0; rep < 32; rep++) {
            float v = x[(b0+rep)*K_ + li*1152 + c0 + lc];
            lds[rep*256 + ((lc*8+li) ^ ((rep&31)<<3))] = f2bf(v);
        }
        __syncthreads();
        // xb2: each thread writes 32 contiguous elems of one b-row
        {
            int b = tid >> 3, part = tid & 7;
            int swz = (b&31) << 3;
            const u16x8v* lv = (const u16x8v*)lds;
            u16x8v* ov = (u16x8v*)(g_xb2 + (b0+b)*K_ + c0*8 + part*32);
            #pragma unroll
            for (int g = 0; g < 4; g++)
                ov[g] = lv[(b*256 + ((part*32 + g*8) ^ swz)) >> 3];
        }
        // xT2: 8 passes; 8 threads cooperate per k'-row -> 64B coalesced rows
        for (int p = 0; p < 8; p++) {
            int r = p*32 + (tid>>3);
            int bp = (tid&7)*4;
            ushort4 o;
            unsigned short* po = (unsigned short*)&o;
            #pragma unroll
            for (int q = 0; q < 4; q++) {
                int b = bp + q;
                po[q] = lds[b*256 + (r ^ ((b&31)<<3))];
            }
            *(ushort4*)(g_xT2 + (c0*8 + r)*B_ + b0 + bp) = o;
        }
    } else {
        int wblk = task - 576;                   // 180 blocks x 8192 elems
        int base = wblk * 8192;
        for (int j = 0; j < 8; j++) {
            float4 v = *(const float4*)(W + base + j*1024 + tid*4);
            ushort4 o;
            o.x = f2bf(0.1f*v.x); o.y = f2bf(0.1f*v.y);
            o.z = f2bf(0.1f*v.z); o.w = f2bf(0.1f*v.w);
            *(ushort4*)(g_Wc + base + j*1024 + tid*4) = o;
        }
    }
}

// ---- S: s = x @ Wc^T  fused with squash -> vT (+ final out) ----
// grid 160 = 32 m-tiles (16 b-rows) x 5 u-pair tiles (32 uo-cols); 4 waves split K.
template<int WRITE_OUT>
__global__ __launch_bounds__(256) void k_s(float* __restrict__ out) {
    __shared__ float red[4][16][32];
    int tid = threadIdx.x, lane = tid & 63, w = tid >> 6;
    int mt = blockIdx.x & 31, nt = blockIdx.x >> 5;
    int m0 = mt*16, n0 = nt*32;
    int ra = lane & 15, kq = (lane>>4)*8;

    const unsigned short* pa  = g_xb2 + (m0+ra)*K_ + w*2304 + kq;
    // B elem addr = c*1280 + n*8 + i ; 8 consecutive k' = i 0..7 at fixed c
    const unsigned short* pb0 = g_Wc + (w*288 + (kq>>3))*1280 + (n0+ra)*8;
    const unsigned short* pb1 = pb0 + 128;      // n+16
    f32x4 acc0 = {0.f,0.f,0.f,0.f};
    f32x4 acc1 = {0.f,0.f,0.f,0.f};
    #pragma unroll 6
    for (int s = 0; s < 72; s++) {              // K/wave = 2304 = 72*32
        bf16x8 a  = *(const bf16x8*)pa;
        bf16x8 b0 = *(const bf16x8*)pb0;
        bf16x8 b1 = *(const bf16x8*)pb1;
        acc0 = __builtin_amdgcn_mfma_f32_16x16x32_bf16(a, b0, acc0, 0, 0, 0);
        acc1 = __builtin_amdgcn_mfma_f32_16x16x32_bf16(a, b1, acc1, 0, 0, 0);
        pa += 32; pb0 += 5120; pb1 += 5120;     // +4 channels
    }
    int row = (lane>>4)*4, col = lane & 15;
    #pragma unroll
    for (int r = 0; r < 4; r++) {
        red[w][row+r][col]    = acc0[r];
        red[w][row+r][col+16] = acc1[r];
    }
    __syncthreads();
    // reduce 4 waves + squash.  group g = tid>>3: brow=g&15, uh=g>>4; o=(tid&7)*2
    int g = tid >> 3, brow = g & 15, uh = g >> 4, o = (tid & 7)*2;
    int cA = uh*16 + o, cB = cA + 1;
    float t0 = red[0][brow][cA] + red[1][brow][cA] + red[2][brow][cA] + red[3][brow][cA];
    float t1 = red[0][brow][cB] + red[1][brow][cB] + red[2][brow][cB] + red[3][brow][cB];
    float nrm = t0*t0 + t1*t1;
    nrm += __shfl_xor(nrm, 1);
    nrm += __shfl_xor(nrm, 2);
    nrm += __shfl_xor(nrm, 4);
    float f = nrm / ((1.f + nrm) * sqrtf(nrm));
    float v0 = t0*f, v1 = t1*f;
    int ug = nt*2 + uh, bg = m0 + brow;
    g_vT[(ug*16+o)*B_ + bg]   = f2bf(v0);
    g_vT[(ug*16+o+1)*B_ + bg] = f2bf(v1);
    if (WRITE_OUT) {
        float2 o2; o2.x = v0; o2.y = v1;
        *(float2*)(out + (bg*10 + ug)*16 + o) = o2;
    }
}

// ---- TB: T' = xT2 @ vT^T (in regs) + agree + b-update + softmax + Wc build ----
// grid 576 blocks (channel pair) x 320 threads (5 waves; wave w owns u={2w,2w+1})
__global__ __launch_bounds__(320) void k_tb(const float* __restrict__ W, int first) {
    __shared__ float agg[2][U_];
    __shared__ float cws[2][U_];
    int tid = threadIdx.x, lane = tid & 63, w = tid >> 6;
    int c0 = blockIdx.x * 2;
    int ra = lane & 15, kq = (lane>>4)*8;
    int n0 = w*32;
    const unsigned short* pa  = g_xT2 + (c0*8 + ra)*B_ + kq;
    const unsigned short* pb0 = g_vT + (n0+ra)*B_ + kq;
    const unsigned short* pb1 = pb0 + 16*B_;
    f32x4 acc0 = {0.f,0.f,0.f,0.f};
    f32x4 acc1 = {0.f,0.f,0.f,0.f};
    #pragma unroll 4
    for (int s = 0; s < 16; s++) {              // K = 512
        bf16x8 a  = *(const bf16x8*)pa;
        bf16x8 b0 = *(const bf16x8*)pb0;
        bf16x8 b1 = *(const bf16x8*)pb1;
        acc0 = __builtin_amdgcn_mfma_f32_16x16x32_bf16(a, b0, acc0, 0, 0, 0);
        acc1 = __builtin_amdgcn_mfma_f32_16x16x32_bf16(a, b1, acc1, 0, 0, 0);
        pa += 32; pb0 += 32; pb1 += 32;
    }
    // acc row = (lane>>4)*4+r -> channel ct=lane>>5, i = i0+r, i0=(lane>>4&1)*4
    int ct = lane >> 5;
    int i0 = (lane>>4 & 1) * 4;
    int o  = lane & 15;
    const float* wr = W + (c0+ct)*1280;
    float4 wa = *(const float4*)(wr + (2*w  )*128 + o*8 + i0);
    float4 wb = *(const float4*)(wr + (2*w+1)*128 + o*8 + i0);
    float p0 = wa.x*acc0[0] + wa.y*acc0[1] + wa.z*acc0[2] + wa.w*acc0[3];
    float p1 = wb.x*acc1[0] + wb.y*acc1[1] + wb.z*acc1[2] + wb.w*acc1[3];
    #pragma unroll
    for (int m = 1; m < 32; m <<= 1) {
        p0 += __shfl_xor(p0, m);
        p1 += __shfl_xor(p1, m);
    }
    if ((lane & 31) == 0) {
        agg[ct][2*w]   = p0 * (1.f/512.f);
        agg[ct][2*w+1] = p1 * (1.f/512.f);
    }
    __syncthreads();
    if (tid < 2) {                              // per-channel b-update + softmax
        int c = c0 + tid;
        float bv[U_];
        float mx = -3e38f;
        #pragma unroll
        for (int u = 0; u < U_; u++) {
            float v = agg[tid][u];
            if (!first) v += g_b[c*U_ + u];
            g_b[c*U_ + u] = v;
            bv[u] = v;
            mx = fmaxf(mx, v);
        }
        float sm = 0.f;
        #pragma unroll
        for (int u = 0; u < U_; u++) { bv[u] = expf(bv[u] - mx); sm += bv[u]; }
        float inv = 1.f/sm;
        #pragma unroll
        for (int u = 0; u < U_; u++) cws[tid][u] = bv[u]*inv;
    }
    __syncthreads();
    // build next-iter Wc rows for both channels: 2560 elems / 320 threads = 8 each
    int ch  = (tid >= 160) ? 1 : 0;
    int off = (ch ? tid-160 : tid) * 8;
    int u   = off >> 7;
    float s = cws[ch][u];
    const float* wp = W + (c0+ch)*1280 + off;
    float4 a4 = *(const float4*)wp;
    float4 b4 = *(const float4*)(wp + 4);
    u16x8v ov;
    ov[0] = f2bf(a4.x*s); ov[1] = f2bf(a4.y*s); ov[2] = f2bf(a4.z*s); ov[3] = f2bf(a4.w*s);
    ov[4] = f2bf(b4.x*s); ov[5] = f2bf(b4.y*s); ov[6] = f2bf(b4.z*s); ov[7] = f2bf(b4.w*s);
    *(u16x8v*)(g_Wc + (c0+ch)*1280 + off) = ov;
}

extern "C" void kernel_launch(void* const* d_in, const int* in_sizes, int n_in,
                              void* d_out, int out_size, void* d_ws, size_t ws_size,
                              hipStream_t stream) {
    const float* x = (const float*)d_in[0];
    const float* W = (const float*)d_in[1];
    float* out = (float*)d_out;

    k_prep<<<dim3(756), dim3(256), 0, stream>>>(x, W);
    k_s<0><<<dim3(160), dim3(256), 0, stream>>>(nullptr);   // t=0 (Wc = 0.1*W)
    k_tb<<<dim3(576), dim3(320), 0, stream>>>(W, 1);
    k_s<0><<<dim3(160), dim3(256), 0, stream>>>(nullptr);   // t=1
    k_tb<<<dim3(576), dim3(320), 0, stream>>>(W, 0);
    k_s<1><<<dim3(160), dim3(256), 0, stream>>>(out);       // t=2
}